// Round 10
// baseline (135.409 us; speedup 1.0000x reference)
//
#include <hip/hip_runtime.h>
#include <cstdint>
#include <cstddef>

#define D_DIM 320
#define NEGINF (-1e30f)

typedef __attribute__((ext_vector_type(8))) short bf16x8_t;
typedef __attribute__((ext_vector_type(4))) float f32x4_t;

struct Tab {
  int T[11], S[11], zoff[11], wsoff[11];
  int tileStart[12], instStart[12], rstart[11];
  float scale[11];
  int totTemp, totInst, totr;
};

__device__ __forceinline__ float bf2f(unsigned short u) {
  union { unsigned int i; float f; } v; v.i = ((unsigned int)u) << 16; return v.f;
}
__device__ __forceinline__ unsigned short f2bf(float f) {
  union { float f; unsigned int i; } u; u.f = f;
  unsigned int b = u.i + 0x7FFFu + ((u.i >> 16) & 1u);
  return (unsigned short)(b >> 16);
}

__device__ __forceinline__ const unsigned short* zrowb(
    const unsigned short* __restrict__ z1, const unsigned short* __restrict__ z2,
    int b, int T, int r) {
  return (r < T) ? (z1 + ((size_t)b * T + r) * D_DIM)
                 : (z2 + ((size_t)b * T + (r - T)) * D_DIM);
}

#define GLOAD_LDS16(SRC, DST)                                                   \
  __builtin_amdgcn_global_load_lds(                                             \
      (const __attribute__((address_space(1))) void*)(SRC),                     \
      (__attribute__((address_space(3))) void*)(DST), 16, 0, 0)

// ---- shared tile-engine macros (both prep L0-tiles and rest tiles) ----
#define BUFOFS 8192 /* shorts: one staging buffer = 8 planes x 128 rows x 8 */

#define STAGE(koff, bufofs)                                                     \
    do {                                                                        \
      GLOAD_LDS16(gA0 + (koff), dA0 + (bufofs));                                \
      GLOAD_LDS16(gA1 + (koff), dA1 + (bufofs));                                \
      GLOAD_LDS16(gB0 + (koff), dB0 + (bufofs));                                \
      GLOAD_LDS16(gB1 + (koff), dB1 + (bufofs));                                \
    } while (0)

#define PHASE(k, bo, VM, DO_PF)                                                 \
    do {                                                                        \
      asm volatile("s_waitcnt vmcnt(" #VM ")" ::: "memory");                    \
      __builtin_amdgcn_s_barrier();                                             \
      bf16x8_t af[4], bfr[4];                                                   \
      _Pragma("unroll")                                                         \
      for (int at = 0; at < 4; ++at)                                            \
        af[at] = *(const bf16x8_t*)(vA + (bo) + at * 128);                      \
      _Pragma("unroll")                                                         \
      for (int ct = 0; ct < 4; ++ct)                                            \
        bfr[ct] = *(const bf16x8_t*)(vB + (bo) + ct * 128);                     \
      asm volatile("s_waitcnt lgkmcnt(0)" ::: "memory");                        \
      __builtin_amdgcn_sched_barrier(0);                                        \
      __builtin_amdgcn_s_barrier();                                             \
      if (DO_PF) STAGE((k + 2) * 32, bo);                                       \
      __builtin_amdgcn_s_setprio(1);                                            \
      _Pragma("unroll")                                                         \
      for (int ct = 0; ct < 4; ++ct)                                            \
        _Pragma("unroll")                                                       \
        for (int at = 0; at < 4; ++at)                                          \
          acc[at][ct] = __builtin_amdgcn_mfma_f32_16x16x32_bf16(                \
              af[at], bfr[ct], acc[at][ct], 0, 0, 0);                           \
      __builtin_amdgcn_s_setprio(0);                                            \
    } while (0)

// ---------------- fp32 -> bf16 convert (both arrays) + zero out ----------------
__global__ __launch_bounds__(256) void convert_kernel(
    const float* __restrict__ i1, const float* __restrict__ i2,
    unsigned short* __restrict__ o1, unsigned short* __restrict__ o2,
    int n4, float* __restrict__ out, int outn) {
  int i = blockIdx.x * 256 + threadIdx.x;
  if (i < outn) out[i] = 0.f;
  int stride = gridDim.x * 256;
  for (int j = i; j < n4; j += stride) {
    float4 v = ((const float4*)i1)[j];
    ushort4 r;
    r.x = f2bf(v.x); r.y = f2bf(v.y); r.z = f2bf(v.z); r.w = f2bf(v.w);
    ((ushort4*)o1)[j] = r;
    float4 u = ((const float4*)i2)[j];
    ushort4 q;
    q.x = f2bf(u.x); q.y = f2bf(u.y); q.z = f2bf(u.z); q.w = f2bf(u.w);
    ((ushort4*)o2)[j] = q;
  }
}

// ---------------- prep: [8 sort blocks] + [272 L0 tile-quad blocks] +
//                  [64 L0 instance blocks], all 1024-thread ----------------
__global__ __launch_bounds__(1024) void prep_kernel(
    const int* __restrict__ time0, int* __restrict__ sel_all,
    const unsigned short* __restrict__ z1, const unsigned short* __restrict__ z2,
    float* __restrict__ wsm, float* __restrict__ wss,
    float* __restrict__ wsInst) {
  __shared__ __align__(16) unsigned char smem[147456];
  int bx = blockIdx.x;
  int tid = threadIdx.x;

  if (bx < 8) {
    // ========== all-levels stable sort + selection + time chain ==========
    int b = bx;
    int lane = tid & 63, wid = tid >> 6;
    int* tcur = (int*)smem;                                   // 4096 B
    unsigned long long* kl = (unsigned long long*)(smem + 4096);  // 8192 B
    int* wcnt = (int*)(smem + 12288);                         // 64 B
    int* tnew = (int*)(smem + 12352);                         // 2048 B

    tcur[tid] = time0[b * 1024 + tid];
    __syncthreads();

    int off = 0;
    for (int T = 1024; T >= 2; T >>= 1) {
      int n = T - 1, half = T >> 1;
      unsigned long long key = ~0ULL;
      if (tid < n) {
        unsigned d = (unsigned)(tcur[tid + 1] - tcur[tid]);
        key = ((unsigned long long)d << 10) | (unsigned)tid;
      }
      for (int size = 2; size <= T; size <<= 1) {
        bool up = ((tid & size) == 0);
        for (int stride = size >> 1; stride > 0; stride >>= 1) {
          bool lower = ((tid & stride) == 0);
          bool takemin = (lower == up);
          if (stride >= 64) {
            if (tid < T) kl[tid] = key;
            __syncthreads();
            if (tid < T) {
              unsigned long long pk = kl[tid ^ stride];
              unsigned long long mn = key < pk ? key : pk;
              unsigned long long mx = key < pk ? pk : key;
              key = takemin ? mn : mx;
            }
            __syncthreads();
          } else {
            unsigned klo = (unsigned)key, khi = (unsigned)(key >> 32);
            unsigned plo = __shfl_xor((int)klo, stride);
            unsigned phi = __shfl_xor((int)khi, stride);
            unsigned long long pk = ((unsigned long long)phi << 32) | plo;
            unsigned long long mn = key < pk ? key : pk;
            unsigned long long mx = key < pk ? pk : key;
            key = takemin ? mn : mx;
          }
        }
      }
      int p = (int)(key & 1023ULL);
      bool mask = (tid < n) && (p < half);
      unsigned long long bal = __ballot(mask);
      int rw = __popcll(bal & ((1ull << lane) - 1ull));
      if (lane == 0) wcnt[wid] = (int)__popcll(bal);
      __syncthreads();
      int pre = 0;
      for (int i = 0; i < wid; ++i) pre += wcnt[i];
      if (mask) {
        int rank = pre + rw;
        sel_all[off + b * half + rank] = tid;
        tnew[rank] = (tcur[tid] + tcur[tid + 1]) >> 1;
      }
      __syncthreads();
      if (tid < half) tcur[tid] = tnew[tid];
      off += 8 * half;
      __syncthreads();
    }
  } else if (bx < 280) {
    // ========== level-0 temporal: four independent 128x128 tiles ==========
    const int T = 1024, N = 2048, S = 16;
    int sub = tid >> 8;
    int stid = tid & 255;
    int local = bx - 8;
    int b = local % 8;                         // one batch per XCD
    int pr = (local / 8) * 4 + sub;            // 0..135 (triangular index)
    int rb = 0, tt = pr;
    while (tt >= S - rb) { tt -= S - rb; ++rb; }
    int sg = rb + tt;
    int row0 = rb * 128, col0 = sg * 128;

    int w = stid >> 6, lane = tid & 63;
    int lq = lane >> 4, lr = lane & 15;
    int wr = w >> 1, wc = w & 1;

    unsigned char* base = smem + sub * 36864;
    unsigned short* lds = (unsigned short*)base;
    float (*mS)[128] = (float(*)[128])(base + 32768);
    float (*sS)[128] = (float(*)[128])(base + 33792);
    float (*mC)[128] = (float(*)[128])(base + 34816);
    float (*sC)[128] = (float(*)[128])(base + 35840);

    const unsigned short* gA0 = zrowb(z1, z2, b, T, row0 + lane) + w * 8;
    const unsigned short* gA1 = zrowb(z1, z2, b, T, row0 + 64 + lane) + w * 8;
    const unsigned short* gB0 = zrowb(z1, z2, b, T, col0 + lane) + w * 8;
    const unsigned short* gB1 = zrowb(z1, z2, b, T, col0 + 64 + lane) + w * 8;
    unsigned short* dA0 = &lds[((w) * 128 + lane) * 8];
    unsigned short* dA1 = &lds[((w) * 128 + 64 + lane) * 8];
    unsigned short* dB0 = &lds[((4 + w) * 128 + lane) * 8];
    unsigned short* dB1 = &lds[((4 + w) * 128 + 64 + lane) * 8];

    f32x4_t acc[4][4];
#pragma unroll
    for (int at = 0; at < 4; ++at)
#pragma unroll
      for (int ct = 0; ct < 4; ++ct) acc[at][ct] = (f32x4_t)(0.f);

    const unsigned short* vA = &lds[((lq) * 128 + wr * 64 + lr) * 8];
    const unsigned short* vB = &lds[((4 + lq) * 128 + wc * 64 + lr) * 8];

    STAGE(0, 0);
    STAGE(32, BUFOFS);
    for (int k = 0; k < 8; k += 2) {
      PHASE(k, 0, 4, 1);
      PHASE(k + 1, BUFOFS, 4, 1);
    }
    PHASE(8, 0, 4, 0);
    PHASE(9, BUFOFS, 0, 0);
    __builtin_amdgcn_s_barrier();

    // row-LSE -> partial (col-seg sg)
#pragma unroll
    for (int at = 0; at < 4; ++at) {
#pragma unroll
      for (int rg = 0; rg < 4; ++rg) {
        int rloc = wr * 64 + at * 16 + lq * 4 + rg;
        int rglob = row0 + rloc;
        float v[4];
#pragma unroll
        for (int ct = 0; ct < 4; ++ct) {
          int cg = col0 + wc * 64 + ct * 16 + lr;
          v[ct] = (cg != rglob) ? acc[at][ct][rg] : NEGINF;
        }
        float m = fmaxf(fmaxf(v[0], v[1]), fmaxf(v[2], v[3]));
#pragma unroll
        for (int o = 1; o < 16; o <<= 1) m = fmaxf(m, __shfl_xor(m, o));
        float sv = __expf(v[0] - m) + __expf(v[1] - m) +
                   __expf(v[2] - m) + __expf(v[3] - m);
#pragma unroll
        for (int o = 1; o < 16; o <<= 1) sv += __shfl_xor(sv, o);
        if (lr == 0) { mS[wc][rloc] = m; sS[wc][rloc] = sv; }
      }
    }
    // col-LSE (symmetry) -> partial (col-seg rb)
    if (rb != sg) {
#pragma unroll
      for (int ct = 0; ct < 4; ++ct) {
        float m = NEGINF;
#pragma unroll
        for (int at = 0; at < 4; ++at)
#pragma unroll
          for (int rg = 0; rg < 4; ++rg) m = fmaxf(m, acc[at][ct][rg]);
        m = fmaxf(m, __shfl_xor(m, 16));
        m = fmaxf(m, __shfl_xor(m, 32));
        float s = 0.f;
#pragma unroll
        for (int at = 0; at < 4; ++at)
#pragma unroll
          for (int rg = 0; rg < 4; ++rg) s += __expf(acc[at][ct][rg] - m);
        s += __shfl_xor(s, 16);
        s += __shfl_xor(s, 32);
        if (lq == 0) {
          mC[wr][wc * 64 + ct * 16 + lr] = m;
          sC[wr][wc * 64 + ct * 16 + lr] = s;
        }
      }
    }
    __syncthreads();

    if (stid < 128) {
      {
        float m0 = mS[0][stid], m1 = mS[1][stid];
        float m = fmaxf(m0, m1);
        float sv = sS[0][stid] * __expf(m0 - m) + sS[1][stid] * __expf(m1 - m);
        int idx = (b * S + sg) * N + row0 + stid;
        wsm[idx] = m;
        wss[idx] = sv;
      }
      if (rb != sg) {
        float m0 = mC[0][stid], m1 = mC[1][stid];
        float m = fmaxf(m0, m1);
        float sv = sC[0][stid] * __expf(m0 - m) + sC[1][stid] * __expf(m1 - m);
        int idx = (b * S + rb) * N + col0 + stid;
        wsm[idx] = m;
        wss[idx] = sv;
      }
    }
  } else {
    // ========== level-0 instance: one wave per t ==========
    int iw = (bx - 280) * 16 + (tid >> 6);  // 0..1023
    int t = iw;
    int lane = tid & 63, lq = lane >> 4, lr = lane & 15;
    const unsigned short* zr = (lr < 8)
        ? z1 + ((size_t)lr * 1024 + t) * D_DIM
        : z2 + ((size_t)(lr - 8) * 1024 + t) * D_DIM;
    zr += lq * 8;
    f32x4_t c = (f32x4_t)(0.f);
#pragma unroll
    for (int k = 0; k < 10; ++k) {
      bf16x8_t a = *(const bf16x8_t*)(zr + k * 32);
      c = __builtin_amdgcn_mfma_f32_16x16x32_bf16(a, a, c, 0, 0, 0);
    }
    float lsum = 0.f;
#pragma unroll
    for (int rg = 0; rg < 4; ++rg) {
      int rrow = lq * 4 + rg;
      float v = c[rg];
      float x = (lr != rrow) ? v : NEGINF;
      float m = x;
#pragma unroll
      for (int o = 1; o < 16; o <<= 1) m = fmaxf(m, __shfl_xor(m, o));
      float s = __expf(x - m);
#pragma unroll
      for (int o = 1; o < 16; o <<= 1) s += __shfl_xor(s, o);
      int pos = (rrow < 8) ? rrow + 8 : rrow - 8;
      if (lr == pos) lsum += m + __logf(s) - v;
    }
#pragma unroll
    for (int o = 1; o < 64; o <<= 1) lsum += __shfl_xor(lsum, o);
    if (lane == 0) wsInst[iw] = lsum * (1.0f / 360448.0f);  // 352*1024
  }
}

// ---------------- pool chain: LDS-resident 8-col d-slice, 10 levels ----------
__global__ __launch_bounds__(256, 4) void poolchain_kernel(
    const int* __restrict__ sel_all,
    unsigned short* __restrict__ z1, unsigned short* __restrict__ z2) {
  int bx = blockIdx.x;
  int tid = threadIdx.x;
  int chunk = bx % 40;
  int zi = (bx / 40) & 1;
  int b = bx / 80;
  unsigned short* z = (zi == 0) ? z1 : z2;

  __shared__ unsigned short zsA[1024][8];
  __shared__ unsigned short zsB[512][8];

  const unsigned short* src0 = z + ((size_t)b * 1024) * D_DIM + chunk * 8;
  for (int r = tid; r < 1024; r += 256)
    *(bf16x8_t*)&zsA[r][0] = *(const bf16x8_t*)(src0 + (size_t)r * D_DIM);
  __syncthreads();

  int off = 0;
  size_t zo = (size_t)8 * 1024 * D_DIM;
  for (int l = 0; l < 10; ++l) {
    int T = 1024 >> l, half = T >> 1;
    const int* selp = sel_all + off + b * half;
    unsigned short* dst = z + zo + ((size_t)b * half) * D_DIM + chunk * 8;
    bool AtoB = ((l & 1) == 0);
    for (int j = tid; j < half; j += 256) {
      int k = selp[j];
      bf16x8_t a, c;
      if (AtoB) { a = *(const bf16x8_t*)&zsA[k][0]; c = *(const bf16x8_t*)&zsA[k + 1][0]; }
      else      { a = *(const bf16x8_t*)&zsB[k][0]; c = *(const bf16x8_t*)&zsB[k + 1][0]; }
      bf16x8_t rv;
#pragma unroll
      for (int e = 0; e < 8; ++e)
        rv[e] = (bf2f((unsigned short)a[e]) >= bf2f((unsigned short)c[e])) ? a[e] : c[e];
      *(bf16x8_t*)(dst + (size_t)j * D_DIM) = rv;
      if (AtoB) *(bf16x8_t*)&zsB[j][0] = rv;
      else      *(bf16x8_t*)&zsA[j][0] = rv;
    }
    __syncthreads();
    off += 8 * half;
    zo += (size_t)8 * half * D_DIM;
  }
}

// ---------------- rest: levels 1..10 temporal tiles + instance waves ----------
__global__ __launch_bounds__(256, 4) void rest_kernel(
    const unsigned short* __restrict__ z1, const unsigned short* __restrict__ z2,
    float* __restrict__ wsm, float* __restrict__ wss,
    float* __restrict__ wsInst, Tab tab) {
  __shared__ __align__(16) unsigned char smem[36864];
  int bx = blockIdx.x;
  int tid = threadIdx.x;
  int nTiles = tab.totTemp - tab.tileStart[1];

  if (bx < nTiles) {
    int g = tab.tileStart[1] + bx;
    int l = 1;
    while (g >= tab.tileStart[l + 1]) ++l;
    int T = tab.T[l], S = tab.S[l];
    int N = 2 * T;
    const unsigned short* zz1 = z1 + tab.zoff[l];
    const unsigned short* zz2 = z2 + tab.zoff[l];
    float* wm = wsm + tab.wsoff[l];
    float* wv = wss + tab.wsoff[l];

    int local = g - tab.tileStart[l];
    int npl = (S * (S + 1)) >> 1;
    int nid = (local % 8) * npl + local / 8;
    int b = nid / npl;
    int pr = nid % npl;
    int rb = 0, tt = pr;
    while (tt >= S - rb) { tt -= S - rb; ++rb; }
    int sg = rb + tt;
    int row0 = rb * 128, col0 = sg * 128;

    int w = tid >> 6, lane = tid & 63;
    int lq = lane >> 4, lr = lane & 15;
    int wr = w >> 1, wc = w & 1;

    unsigned short* lds = (unsigned short*)smem;
    float (*mS)[128] = (float(*)[128])(smem + 32768);
    float (*sS)[128] = (float(*)[128])(smem + 33792);
    float (*mC)[128] = (float(*)[128])(smem + 34816);
    float (*sC)[128] = (float(*)[128])(smem + 35840);

    int ra0 = row0 + lane;        if (ra0 > N - 1) ra0 = N - 1;
    int ra1 = row0 + 64 + lane;   if (ra1 > N - 1) ra1 = N - 1;
    int ca0 = col0 + lane;        if (ca0 > N - 1) ca0 = N - 1;
    int ca1 = col0 + 64 + lane;   if (ca1 > N - 1) ca1 = N - 1;
    const unsigned short* gA0 = zrowb(zz1, zz2, b, T, ra0) + w * 8;
    const unsigned short* gA1 = zrowb(zz1, zz2, b, T, ra1) + w * 8;
    const unsigned short* gB0 = zrowb(zz1, zz2, b, T, ca0) + w * 8;
    const unsigned short* gB1 = zrowb(zz1, zz2, b, T, ca1) + w * 8;
    unsigned short* dA0 = &lds[((w) * 128 + lane) * 8];
    unsigned short* dA1 = &lds[((w) * 128 + 64 + lane) * 8];
    unsigned short* dB0 = &lds[((4 + w) * 128 + lane) * 8];
    unsigned short* dB1 = &lds[((4 + w) * 128 + 64 + lane) * 8];

    f32x4_t acc[4][4];
#pragma unroll
    for (int at = 0; at < 4; ++at)
#pragma unroll
      for (int ct = 0; ct < 4; ++ct) acc[at][ct] = (f32x4_t)(0.f);

    const unsigned short* vA = &lds[((lq) * 128 + wr * 64 + lr) * 8];
    const unsigned short* vB = &lds[((4 + lq) * 128 + wc * 64 + lr) * 8];

    STAGE(0, 0);
    STAGE(32, BUFOFS);
    for (int k = 0; k < 8; k += 2) {
      PHASE(k, 0, 4, 1);
      PHASE(k + 1, BUFOFS, 4, 1);
    }
    PHASE(8, 0, 4, 0);
    PHASE(9, BUFOFS, 0, 0);
    __builtin_amdgcn_s_barrier();

#pragma unroll
    for (int at = 0; at < 4; ++at) {
#pragma unroll
      for (int rg = 0; rg < 4; ++rg) {
        int rloc = wr * 64 + at * 16 + lq * 4 + rg;
        int rglob = row0 + rloc;
        float v[4];
#pragma unroll
        for (int ct = 0; ct < 4; ++ct) {
          int cg = col0 + wc * 64 + ct * 16 + lr;
          v[ct] = (cg < N && cg != rglob) ? acc[at][ct][rg] : NEGINF;
        }
        float m = fmaxf(fmaxf(v[0], v[1]), fmaxf(v[2], v[3]));
#pragma unroll
        for (int o = 1; o < 16; o <<= 1) m = fmaxf(m, __shfl_xor(m, o));
        float sv = __expf(v[0] - m) + __expf(v[1] - m) +
                   __expf(v[2] - m) + __expf(v[3] - m);
#pragma unroll
        for (int o = 1; o < 16; o <<= 1) sv += __shfl_xor(sv, o);
        if (lr == 0) { mS[wc][rloc] = m; sS[wc][rloc] = sv; }
      }
    }
    if (rb != sg) {
#pragma unroll
      for (int ct = 0; ct < 4; ++ct) {
        float m = NEGINF;
#pragma unroll
        for (int at = 0; at < 4; ++at)
#pragma unroll
          for (int rg = 0; rg < 4; ++rg) m = fmaxf(m, acc[at][ct][rg]);
        m = fmaxf(m, __shfl_xor(m, 16));
        m = fmaxf(m, __shfl_xor(m, 32));
        float s = 0.f;
#pragma unroll
        for (int at = 0; at < 4; ++at)
#pragma unroll
          for (int rg = 0; rg < 4; ++rg) s += __expf(acc[at][ct][rg] - m);
        s += __shfl_xor(s, 16);
        s += __shfl_xor(s, 32);
        if (lq == 0) {
          mC[wr][wc * 64 + ct * 16 + lr] = m;
          sC[wr][wc * 64 + ct * 16 + lr] = s;
        }
      }
    }
    __syncthreads();

    if (tid < 128) {
      int rglob = row0 + tid;
      if (rglob < N) {
        float m0 = mS[0][tid], m1 = mS[1][tid];
        float m = fmaxf(m0, m1);
        float sv = sS[0][tid] * __expf(m0 - m) + sS[1][tid] * __expf(m1 - m);
        int idx = (b * S + sg) * N + rglob;
        wm[idx] = m;
        wv[idx] = sv;
      }
      if (rb != sg) {
        float m0 = mC[0][tid], m1 = mC[1][tid];
        float m = fmaxf(m0, m1);
        float sv = sC[0][tid] * __expf(m0 - m) + sC[1][tid] * __expf(m1 - m);
        int idx = (b * S + rb) * N + col0 + tid;
        wm[idx] = m;
        wv[idx] = sv;
      }
    }
  } else {
    // instance levels 1..10: one wave per t
    int iw = 1024 + (bx - nTiles) * 4 + (tid >> 6);
    if (iw < tab.totInst) {
      int l = 1;
      while (iw >= tab.instStart[l + 1]) ++l;
      int t = iw - tab.instStart[l];
      int T = tab.T[l];
      const unsigned short* zz1 = z1 + tab.zoff[l];
      const unsigned short* zz2 = z2 + tab.zoff[l];
      int lane = tid & 63, lq = lane >> 4, lr = lane & 15;
      const unsigned short* zr = (lr < 8)
          ? zz1 + ((size_t)lr * T + t) * D_DIM
          : zz2 + ((size_t)(lr - 8) * T + t) * D_DIM;
      zr += lq * 8;
      f32x4_t c = (f32x4_t)(0.f);
#pragma unroll
      for (int k = 0; k < 10; ++k) {
        bf16x8_t a = *(const bf16x8_t*)(zr + k * 32);
        c = __builtin_amdgcn_mfma_f32_16x16x32_bf16(a, a, c, 0, 0, 0);
      }
      float lsum = 0.f;
#pragma unroll
      for (int rg = 0; rg < 4; ++rg) {
        int rrow = lq * 4 + rg;
        float v = c[rg];
        float x = (lr != rrow) ? v : NEGINF;
        float m = x;
#pragma unroll
        for (int o = 1; o < 16; o <<= 1) m = fmaxf(m, __shfl_xor(m, o));
        float s = __expf(x - m);
#pragma unroll
        for (int o = 1; o < 16; o <<= 1) s += __shfl_xor(s, o);
        int pos = (rrow < 8) ? rrow + 8 : rrow - 8;
        if (lr == pos) lsum += m + __logf(s) - v;
      }
#pragma unroll
      for (int o = 1; o < 64; o <<= 1) lsum += __shfl_xor(lsum, o);
      if (lane == 0) wsInst[iw] = lsum * tab.scale[l];
    }
  }
}

// ---------------- combine: temporal rows + instance partials -> out ----------
__global__ __launch_bounds__(256) void combine_kernel(
    const unsigned short* __restrict__ z1, const unsigned short* __restrict__ z2,
    const float* __restrict__ wsm, const float* __restrict__ wss,
    const float* __restrict__ wsInst, float* __restrict__ out, Tab tab) {
  int g = blockIdx.x * 256 + threadIdx.x;
  float loss = 0.f;
  if (g < tab.totr) {
    int l = 0;
    while (g >= tab.rstart[l + 1]) ++l;
    int row = g - tab.rstart[l];
    int T = tab.T[l], N = 2 * T, S = tab.S[l];
    int b = row / N, r = row % N;
    const float* wm = wsm + tab.wsoff[l];
    const float* wv = wss + tab.wsoff[l];
    float m = NEGINF;
    for (int s = 0; s < S; ++s) m = fmaxf(m, wm[(b * S + s) * N + r]);
    float sv = 0.f;
    for (int s = 0; s < S; ++s) {
      int idx = (b * S + s) * N + r;
      sv += wv[idx] * __expf(wm[idx] - m);
    }
    const unsigned short* zz1 = z1 + tab.zoff[l];
    const unsigned short* zz2 = z2 + tab.zoff[l];
    int pos = (r < T) ? r + T : r - T;
    const bf16x8_t* za = (const bf16x8_t*)zrowb(zz1, zz2, b, T, r);
    const bf16x8_t* zp = (const bf16x8_t*)zrowb(zz1, zz2, b, T, pos);
    float dot = 0.f;
    for (int k = 0; k < D_DIM / 8; ++k) {
      bf16x8_t a = za[k], p = zp[k];
#pragma unroll
      for (int e = 0; e < 8; ++e)
        dot += bf2f((unsigned short)a[e]) * bf2f((unsigned short)p[e]);
    }
    loss = (m + logf(sv) - dot) * tab.scale[l];
  } else if (g < tab.totr + tab.totInst) {
    loss = wsInst[g - tab.totr];
  }
  float v = loss;
#pragma unroll
  for (int o = 1; o < 64; o <<= 1) v += __shfl_xor(v, o);
  __shared__ float part[4];
  int w = threadIdx.x >> 6;
  if ((threadIdx.x & 63) == 0) part[w] = v;
  __syncthreads();
  if (threadIdx.x == 0)
    atomicAdd(out, part[0] + part[1] + part[2] + part[3]);
}

extern "C" void kernel_launch(void* const* d_in, const int* in_sizes, int n_in,
                              void* d_out, int out_size, void* d_ws, size_t ws_size,
                              hipStream_t stream) {
  const float* z1_in = (const float*)d_in[0];
  const float* z2_in = (const float*)d_in[1];
  const int* time_in = (const int*)d_in[2];
  float* out = (float*)d_out;

  // ---- level tables (triangular tile counts) ----
  Tab tab;
  int zo = 0, wso = 0, ts = 0, is = 0, rs = 0;
  for (int l = 0; l < 11; ++l) {
    int T = 1024 >> l, N = 2 * T;
    int S = (N >= 128) ? N / 128 : 1;
    tab.T[l] = T;
    tab.S[l] = S;
    tab.zoff[l] = zo;
    tab.scale[l] = 1.0f / (352.0f * (float)T);  // 0.5/(2*B*T)/11
    tab.tileStart[l] = ts;
    tab.instStart[l] = is;
    tab.wsoff[l] = (T > 1) ? wso : 0;
    if (l < 10) tab.rstart[l] = rs;
    if (T > 1) {
      ts += 8 * ((S * (S + 1)) >> 1);
      wso += 8 * S * N;
      rs += 8 * N;
    }
    is += T;
    zo += 8 * T * D_DIM;
  }
  tab.tileStart[11] = ts;
  tab.instStart[11] = is;
  tab.rstart[10] = rs;
  tab.totTemp = ts;
  tab.totInst = is;
  tab.totr = rs;

  // ---- workspace carve ----
  char* w = (char*)d_ws;
  unsigned short* z1s = (unsigned short*)w; w += (size_t)zo * 2;
  unsigned short* z2s = (unsigned short*)w; w += (size_t)zo * 2;
  int* sel_all = (int*)w; w += 8192 * sizeof(int);
  float* wsm = (float*)w; w += (size_t)wso * sizeof(float);
  float* wss = (float*)w; w += (size_t)wso * sizeof(float);
  float* wsInst = (float*)w; w += (size_t)is * sizeof(float);

  int n0 = 8 * 1024 * D_DIM;
  convert_kernel<<<2048, 256, 0, stream>>>(z1_in, z2_in, z1s, z2s, n0 / 4,
                                           out, out_size);
  prep_kernel<<<344, 1024, 0, stream>>>(time_in, sel_all, z1s, z2s,
                                        wsm, wss, wsInst);
  poolchain_kernel<<<640, 256, 0, stream>>>(sel_all, z1s, z2s);
  int nInstB = (tab.totInst - 1024 + 3) / 4;
  rest_kernel<<<(tab.totTemp - tab.tileStart[1]) + nInstB, 256, 0, stream>>>(
      z1s, z2s, wsm, wss, wsInst, tab);
  combine_kernel<<<(tab.totr + tab.totInst + 255) / 256, 256, 0, stream>>>(
      z1s, z2s, wsm, wss, wsInst, out, tab);
}

// Round 11
// 127.317 us; speedup vs baseline: 1.0636x; 1.0636x over previous
//
#include <hip/hip_runtime.h>
#include <cstdint>
#include <cstddef>

#define D_DIM 320
#define NEGINF (-1e30f)

typedef __attribute__((ext_vector_type(8))) short bf16x8_t;
typedef __attribute__((ext_vector_type(4))) float f32x4_t;

struct Tab {
  int T[11], S[11], zoff[11], wsoff[11];
  int tileStart[12], instStart[12], rstart[11];
  float scale[11];
  int totTemp, totInst, totr;
};

__device__ __forceinline__ float bf2f(unsigned short u) {
  union { unsigned int i; float f; } v; v.i = ((unsigned int)u) << 16; return v.f;
}
__device__ __forceinline__ unsigned short f2bf(float f) {
  union { float f; unsigned int i; } u; u.f = f;
  unsigned int b = u.i + 0x7FFFu + ((u.i >> 16) & 1u);
  return (unsigned short)(b >> 16);
}

__device__ __forceinline__ const unsigned short* zrowb(
    const unsigned short* __restrict__ z1, const unsigned short* __restrict__ z2,
    int b, int T, int r) {
  return (r < T) ? (z1 + ((size_t)b * T + r) * D_DIM)
                 : (z2 + ((size_t)b * T + (r - T)) * D_DIM);
}

#define GLOAD_LDS16(SRC, DST)                                                   \
  __builtin_amdgcn_global_load_lds(                                             \
      (const __attribute__((address_space(1))) void*)(SRC),                     \
      (__attribute__((address_space(3))) void*)(DST), 16, 0, 0)

// ---- shared tile-engine macros ----
#define BUFOFS 8192 /* shorts: one staging buffer = 8 planes x 128 rows x 8 */

#define STAGE(koff, bufofs)                                                     \
    do {                                                                        \
      GLOAD_LDS16(gA0 + (koff), dA0 + (bufofs));                                \
      GLOAD_LDS16(gA1 + (koff), dA1 + (bufofs));                                \
      GLOAD_LDS16(gB0 + (koff), dB0 + (bufofs));                                \
      GLOAD_LDS16(gB1 + (koff), dB1 + (bufofs));                                \
    } while (0)

#define PHASE(k, bo, VM, DO_PF)                                                 \
    do {                                                                        \
      asm volatile("s_waitcnt vmcnt(" #VM ")" ::: "memory");                    \
      __builtin_amdgcn_s_barrier();                                             \
      bf16x8_t af[4], bfr[4];                                                   \
      _Pragma("unroll")                                                         \
      for (int at = 0; at < 4; ++at)                                            \
        af[at] = *(const bf16x8_t*)(vA + (bo) + at * 128);                      \
      _Pragma("unroll")                                                         \
      for (int ct = 0; ct < 4; ++ct)                                            \
        bfr[ct] = *(const bf16x8_t*)(vB + (bo) + ct * 128);                     \
      asm volatile("s_waitcnt lgkmcnt(0)" ::: "memory");                        \
      __builtin_amdgcn_sched_barrier(0);                                        \
      __builtin_amdgcn_s_barrier();                                             \
      if (DO_PF) STAGE((k + 2) * 32, bo);                                       \
      __builtin_amdgcn_s_setprio(1);                                            \
      _Pragma("unroll")                                                         \
      for (int ct = 0; ct < 4; ++ct)                                            \
        _Pragma("unroll")                                                       \
        for (int at = 0; at < 4; ++at)                                          \
          acc[at][ct] = __builtin_amdgcn_mfma_f32_16x16x32_bf16(                \
              af[at], bfr[ct], acc[at][ct], 0, 0, 0);                           \
      __builtin_amdgcn_s_setprio(0);                                            \
    } while (0)

// ---------------- prep: [8 bucket-rank sort blocks] + [convert blocks] -------
__global__ __launch_bounds__(1024) void prep_kernel(
    const int* __restrict__ time0, int* __restrict__ sel_all,
    const float* __restrict__ i1, const float* __restrict__ i2,
    unsigned short* __restrict__ o1, unsigned short* __restrict__ o2,
    int n4, float* __restrict__ out, int outn, int nconv) {
  int bx = blockIdx.x;
  int tid = threadIdx.x;

  if (bx < 8) {
    // ========== bucket-rank exact stable argsort, all 10 levels ==========
    int b = bx;
    int lane = tid & 63, wid = tid >> 6;
    __shared__ int tcur[1024];
    __shared__ unsigned hist[1024];
    __shared__ unsigned cum[1024];
    __shared__ unsigned long long arr[1024];
    __shared__ int sortedIdx[1024];
    __shared__ int tnew[512];
    __shared__ unsigned minW[16], maxW[16];
    __shared__ int wcnt[16];

    tcur[tid] = time0[b * 1024 + tid];
    __syncthreads();

    int off = 0;
    for (int T = 1024; T >= 2; T >>= 1) {
      int n = T - 1, half = T >> 1;
      bool act = tid < n;
      int d = 0;
      unsigned bkey = 0;
      if (act) {
        d = tcur[tid + 1] - tcur[tid];
        bkey = __float_as_uint((float)d);  // exact-monotone for d in [0,2^24)
      }
      unsigned mn = act ? bkey : 0xFFFFFFFFu;
      unsigned mx = act ? bkey : 0u;
#pragma unroll
      for (int o = 1; o < 64; o <<= 1) {
        unsigned m2 = (unsigned)__shfl_xor((int)mn, o);
        unsigned x2 = (unsigned)__shfl_xor((int)mx, o);
        mn = mn < m2 ? mn : m2;
        mx = mx > x2 ? mx : x2;
      }
      if (lane == 0) { minW[wid] = mn; maxW[wid] = mx; }
      hist[tid] = 0;
      __syncthreads();

      unsigned bmin = 0xFFFFFFFFu, bmax = 0;
      for (int i = 0; i < 16; ++i) {
        bmin = bmin < minW[i] ? bmin : minW[i];
        bmax = bmax > maxW[i] ? bmax : maxW[i];
      }
      unsigned long long range = (unsigned long long)(bmax - bmin) + 1;
      unsigned long long scale = (1024ULL << 30) / range;
      int bkt = 0;
      unsigned a = 0;
      if (act) {
        bkt = (int)(((unsigned long long)(bkey - bmin) * scale) >> 30);
        if (bkt > 1023) bkt = 1023;
        a = atomicAdd(&hist[bkt], 1u);
      }
      __syncthreads();

      // exclusive prefix over 1024 bins: wave 0, 16 bins/lane
      if (tid < 64) {
        unsigned loc[16];
        unsigned s = 0;
#pragma unroll
        for (int j = 0; j < 16; ++j) { loc[j] = hist[tid * 16 + j]; s += loc[j]; }
        unsigned inc = s;
#pragma unroll
        for (int o = 1; o < 64; o <<= 1) {
          unsigned t = (unsigned)__shfl_up((int)inc, o);
          if (lane >= o) inc += t;
        }
        unsigned ex = inc - s;
#pragma unroll
        for (int j = 0; j < 16; ++j) { cum[tid * 16 + j] = ex; ex += loc[j]; }
      }
      __syncthreads();

      unsigned long long mykey = 0;
      int pos0 = 0;
      if (act) {
        pos0 = (int)cum[bkt];
        mykey = ((unsigned long long)(unsigned)d << 10) | (unsigned)tid;
        arr[pos0 + (int)a] = mykey;
      }
      __syncthreads();

      if (act) {
        int occ = (int)hist[bkt];
        int c = 0;
        for (int j = 0; j < occ; ++j) c += (arr[pos0 + j] < mykey) ? 1 : 0;
        sortedIdx[pos0 + c] = tid;  // rank -> original index
      }
      __syncthreads();

      // mask at rank k=tid: original index of rank-k element < half
      bool m = act && (sortedIdx[tid] < half);
      unsigned long long bal = __ballot(m);
      int rw = __popcll(bal & ((1ull << lane) - 1ull));
      if (lane == 0) wcnt[wid] = (int)__popcll(bal);
      __syncthreads();
      int pre = 0;
      for (int i = 0; i < wid; ++i) pre += wcnt[i];
      if (m) {
        int rr = pre + rw;
        sel_all[off + b * half + rr] = tid;
        tnew[rr] = (tcur[tid] + tcur[tid + 1]) >> 1;
      }
      __syncthreads();
      if (tid < half) tcur[tid] = tnew[tid];
      off += 8 * half;
      __syncthreads();
    }
  } else {
    // ---------- fp32 -> bf16 convert (both arrays) + zero out ----------
    int i = (bx - 8) * 1024 + tid;
    if (i < outn) out[i] = 0.f;
    int stride = nconv * 1024;
    for (int j = i; j < n4; j += stride) {
      float4 v = ((const float4*)i1)[j];
      ushort4 r;
      r.x = f2bf(v.x); r.y = f2bf(v.y); r.z = f2bf(v.z); r.w = f2bf(v.w);
      ((ushort4*)o1)[j] = r;
      float4 u = ((const float4*)i2)[j];
      ushort4 q;
      q.x = f2bf(u.x); q.y = f2bf(u.y); q.z = f2bf(u.z); q.w = f2bf(u.w);
      ((ushort4*)o2)[j] = q;
    }
  }
}

// ---------------- l0: [poolchain] + [L0 temporal tiles] + [L0 instance] ------
__global__ __launch_bounds__(256, 4) void l0_kernel(
    const int* __restrict__ sel_all,
    unsigned short* __restrict__ z1, unsigned short* __restrict__ z2,
    float* __restrict__ wsm, float* __restrict__ wss,
    float* __restrict__ wsInst) {
  __shared__ __align__(16) unsigned char smem[36864];
  int bx = blockIdx.x;
  int tid = threadIdx.x;

  if (bx < 640) {
    // ========== pool chain: LDS-resident 8-col d-slice, 10 levels ==========
    int chunk = bx % 40;
    int zi = (bx / 40) & 1;
    int b = bx / 80;
    unsigned short* z = (zi == 0) ? z1 : z2;
    unsigned short (*zsA)[8] = (unsigned short(*)[8])smem;            // 16 KB
    unsigned short (*zsB)[8] = (unsigned short(*)[8])(smem + 16384);  // 8 KB

    const unsigned short* src0 = z + ((size_t)b * 1024) * D_DIM + chunk * 8;
    for (int r = tid; r < 1024; r += 256)
      *(bf16x8_t*)&zsA[r][0] = *(const bf16x8_t*)(src0 + (size_t)r * D_DIM);
    __syncthreads();

    int off = 0;
    size_t zo = (size_t)8 * 1024 * D_DIM;
    for (int l = 0; l < 10; ++l) {
      int T = 1024 >> l, half = T >> 1;
      const int* selp = sel_all + off + b * half;
      unsigned short* dst = z + zo + ((size_t)b * half) * D_DIM + chunk * 8;
      bool AtoB = ((l & 1) == 0);
      for (int j = tid; j < half; j += 256) {
        int k = selp[j];
        bf16x8_t a, c;
        if (AtoB) { a = *(const bf16x8_t*)&zsA[k][0]; c = *(const bf16x8_t*)&zsA[k + 1][0]; }
        else      { a = *(const bf16x8_t*)&zsB[k][0]; c = *(const bf16x8_t*)&zsB[k + 1][0]; }
        bf16x8_t rv;
#pragma unroll
        for (int e = 0; e < 8; ++e)
          rv[e] = (bf2f((unsigned short)a[e]) >= bf2f((unsigned short)c[e])) ? a[e] : c[e];
        *(bf16x8_t*)(dst + (size_t)j * D_DIM) = rv;
        if (AtoB) *(bf16x8_t*)&zsB[j][0] = rv;
        else      *(bf16x8_t*)&zsA[j][0] = rv;
      }
      __syncthreads();
      off += 8 * half;
      zo += (size_t)8 * half * D_DIM;
    }
  } else if (bx < 640 + 1088) {
    // ========== level-0 temporal: one 128x128 tile (rb<=sg) ==========
    const int T = 1024, N = 2048, S = 16;
    int local = bx - 640;
    int b = local % 8;               // one batch per XCD
    int pr = local / 8;              // 0..135 triangular index
    int rb = 0, tt = pr;
    while (tt >= S - rb) { tt -= S - rb; ++rb; }
    int sg = rb + tt;
    int row0 = rb * 128, col0 = sg * 128;

    int w = tid >> 6, lane = tid & 63;
    int lq = lane >> 4, lr = lane & 15;
    int wr = w >> 1, wc = w & 1;

    unsigned short* lds = (unsigned short*)smem;
    float (*mS)[128] = (float(*)[128])(smem + 32768);
    float (*sS)[128] = (float(*)[128])(smem + 33792);
    float (*mC)[128] = (float(*)[128])(smem + 34816);
    float (*sC)[128] = (float(*)[128])(smem + 35840);

    const unsigned short* gA0 = zrowb(z1, z2, b, T, row0 + lane) + w * 8;
    const unsigned short* gA1 = zrowb(z1, z2, b, T, row0 + 64 + lane) + w * 8;
    const unsigned short* gB0 = zrowb(z1, z2, b, T, col0 + lane) + w * 8;
    const unsigned short* gB1 = zrowb(z1, z2, b, T, col0 + 64 + lane) + w * 8;
    unsigned short* dA0 = &lds[((w) * 128 + lane) * 8];
    unsigned short* dA1 = &lds[((w) * 128 + 64 + lane) * 8];
    unsigned short* dB0 = &lds[((4 + w) * 128 + lane) * 8];
    unsigned short* dB1 = &lds[((4 + w) * 128 + 64 + lane) * 8];

    f32x4_t acc[4][4];
#pragma unroll
    for (int at = 0; at < 4; ++at)
#pragma unroll
      for (int ct = 0; ct < 4; ++ct) acc[at][ct] = (f32x4_t)(0.f);

    const unsigned short* vA = &lds[((lq) * 128 + wr * 64 + lr) * 8];
    const unsigned short* vB = &lds[((4 + lq) * 128 + wc * 64 + lr) * 8];

    STAGE(0, 0);
    STAGE(32, BUFOFS);
    for (int k = 0; k < 8; k += 2) {
      PHASE(k, 0, 4, 1);
      PHASE(k + 1, BUFOFS, 4, 1);
    }
    PHASE(8, 0, 4, 0);
    PHASE(9, BUFOFS, 0, 0);
    __builtin_amdgcn_s_barrier();

    // row-LSE -> partial (col-seg sg)
#pragma unroll
    for (int at = 0; at < 4; ++at) {
#pragma unroll
      for (int rg = 0; rg < 4; ++rg) {
        int rloc = wr * 64 + at * 16 + lq * 4 + rg;
        int rglob = row0 + rloc;
        float v[4];
#pragma unroll
        for (int ct = 0; ct < 4; ++ct) {
          int cg = col0 + wc * 64 + ct * 16 + lr;
          v[ct] = (cg != rglob) ? acc[at][ct][rg] : NEGINF;
        }
        float m = fmaxf(fmaxf(v[0], v[1]), fmaxf(v[2], v[3]));
#pragma unroll
        for (int o = 1; o < 16; o <<= 1) m = fmaxf(m, __shfl_xor(m, o));
        float sv = __expf(v[0] - m) + __expf(v[1] - m) +
                   __expf(v[2] - m) + __expf(v[3] - m);
#pragma unroll
        for (int o = 1; o < 16; o <<= 1) sv += __shfl_xor(sv, o);
        if (lr == 0) { mS[wc][rloc] = m; sS[wc][rloc] = sv; }
      }
    }
    // col-LSE (symmetry) -> partial (col-seg rb)
    if (rb != sg) {
#pragma unroll
      for (int ct = 0; ct < 4; ++ct) {
        float m = NEGINF;
#pragma unroll
        for (int at = 0; at < 4; ++at)
#pragma unroll
          for (int rg = 0; rg < 4; ++rg) m = fmaxf(m, acc[at][ct][rg]);
        m = fmaxf(m, __shfl_xor(m, 16));
        m = fmaxf(m, __shfl_xor(m, 32));
        float s = 0.f;
#pragma unroll
        for (int at = 0; at < 4; ++at)
#pragma unroll
          for (int rg = 0; rg < 4; ++rg) s += __expf(acc[at][ct][rg] - m);
        s += __shfl_xor(s, 16);
        s += __shfl_xor(s, 32);
        if (lq == 0) {
          mC[wr][wc * 64 + ct * 16 + lr] = m;
          sC[wr][wc * 64 + ct * 16 + lr] = s;
        }
      }
    }
    __syncthreads();

    if (tid < 128) {
      {
        float m0 = mS[0][tid], m1 = mS[1][tid];
        float m = fmaxf(m0, m1);
        float sv = sS[0][tid] * __expf(m0 - m) + sS[1][tid] * __expf(m1 - m);
        int idx = (b * S + sg) * N + row0 + tid;
        wsm[idx] = m;
        wss[idx] = sv;
      }
      if (rb != sg) {
        float m0 = mC[0][tid], m1 = mC[1][tid];
        float m = fmaxf(m0, m1);
        float sv = sC[0][tid] * __expf(m0 - m) + sC[1][tid] * __expf(m1 - m);
        int idx = (b * S + rb) * N + col0 + tid;
        wsm[idx] = m;
        wss[idx] = sv;
      }
    }
  } else {
    // ========== level-0 instance: one wave per t ==========
    int iw = (bx - 1728) * 4 + (tid >> 6);  // 0..1023
    int t = iw;
    int lane = tid & 63, lq = lane >> 4, lr = lane & 15;
    const unsigned short* zr = (lr < 8)
        ? z1 + ((size_t)lr * 1024 + t) * D_DIM
        : z2 + ((size_t)(lr - 8) * 1024 + t) * D_DIM;
    zr += lq * 8;
    f32x4_t c = (f32x4_t)(0.f);
#pragma unroll
    for (int k = 0; k < 10; ++k) {
      bf16x8_t a = *(const bf16x8_t*)(zr + k * 32);
      c = __builtin_amdgcn_mfma_f32_16x16x32_bf16(a, a, c, 0, 0, 0);
    }
    float lsum = 0.f;
#pragma unroll
    for (int rg = 0; rg < 4; ++rg) {
      int rrow = lq * 4 + rg;
      float v = c[rg];
      float x = (lr != rrow) ? v : NEGINF;
      float m = x;
#pragma unroll
      for (int o = 1; o < 16; o <<= 1) m = fmaxf(m, __shfl_xor(m, o));
      float s = __expf(x - m);
#pragma unroll
      for (int o = 1; o < 16; o <<= 1) s += __shfl_xor(s, o);
      int pos = (rrow < 8) ? rrow + 8 : rrow - 8;
      if (lr == pos) lsum += m + __logf(s) - v;
    }
#pragma unroll
    for (int o = 1; o < 64; o <<= 1) lsum += __shfl_xor(lsum, o);
    if (lane == 0) wsInst[iw] = lsum * (1.0f / 360448.0f);  // 352*1024
  }
}

// ---------------- rest: levels 1..10 temporal tiles + instance waves ----------
__global__ __launch_bounds__(256, 4) void rest_kernel(
    const unsigned short* __restrict__ z1, const unsigned short* __restrict__ z2,
    float* __restrict__ wsm, float* __restrict__ wss,
    float* __restrict__ wsInst, Tab tab) {
  __shared__ __align__(16) unsigned char smem[36864];
  int bx = blockIdx.x;
  int tid = threadIdx.x;
  int nTiles = tab.totTemp - tab.tileStart[1];

  if (bx < nTiles) {
    int g = tab.tileStart[1] + bx;
    int l = 1;
    while (g >= tab.tileStart[l + 1]) ++l;
    int T = tab.T[l], S = tab.S[l];
    int N = 2 * T;
    const unsigned short* zz1 = z1 + tab.zoff[l];
    const unsigned short* zz2 = z2 + tab.zoff[l];
    float* wm = wsm + tab.wsoff[l];
    float* wv = wss + tab.wsoff[l];

    int local = g - tab.tileStart[l];
    int npl = (S * (S + 1)) >> 1;
    int nid = (local % 8) * npl + local / 8;
    int b = nid / npl;
    int pr = nid % npl;
    int rb = 0, tt = pr;
    while (tt >= S - rb) { tt -= S - rb; ++rb; }
    int sg = rb + tt;
    int row0 = rb * 128, col0 = sg * 128;

    int w = tid >> 6, lane = tid & 63;
    int lq = lane >> 4, lr = lane & 15;
    int wr = w >> 1, wc = w & 1;

    unsigned short* lds = (unsigned short*)smem;
    float (*mS)[128] = (float(*)[128])(smem + 32768);
    float (*sS)[128] = (float(*)[128])(smem + 33792);
    float (*mC)[128] = (float(*)[128])(smem + 34816);
    float (*sC)[128] = (float(*)[128])(smem + 35840);

    int ra0 = row0 + lane;        if (ra0 > N - 1) ra0 = N - 1;
    int ra1 = row0 + 64 + lane;   if (ra1 > N - 1) ra1 = N - 1;
    int ca0 = col0 + lane;        if (ca0 > N - 1) ca0 = N - 1;
    int ca1 = col0 + 64 + lane;   if (ca1 > N - 1) ca1 = N - 1;
    const unsigned short* gA0 = zrowb(zz1, zz2, b, T, ra0) + w * 8;
    const unsigned short* gA1 = zrowb(zz1, zz2, b, T, ra1) + w * 8;
    const unsigned short* gB0 = zrowb(zz1, zz2, b, T, ca0) + w * 8;
    const unsigned short* gB1 = zrowb(zz1, zz2, b, T, ca1) + w * 8;
    unsigned short* dA0 = &lds[((w) * 128 + lane) * 8];
    unsigned short* dA1 = &lds[((w) * 128 + 64 + lane) * 8];
    unsigned short* dB0 = &lds[((4 + w) * 128 + lane) * 8];
    unsigned short* dB1 = &lds[((4 + w) * 128 + 64 + lane) * 8];

    f32x4_t acc[4][4];
#pragma unroll
    for (int at = 0; at < 4; ++at)
#pragma unroll
      for (int ct = 0; ct < 4; ++ct) acc[at][ct] = (f32x4_t)(0.f);

    const unsigned short* vA = &lds[((lq) * 128 + wr * 64 + lr) * 8];
    const unsigned short* vB = &lds[((4 + lq) * 128 + wc * 64 + lr) * 8];

    STAGE(0, 0);
    STAGE(32, BUFOFS);
    for (int k = 0; k < 8; k += 2) {
      PHASE(k, 0, 4, 1);
      PHASE(k + 1, BUFOFS, 4, 1);
    }
    PHASE(8, 0, 4, 0);
    PHASE(9, BUFOFS, 0, 0);
    __builtin_amdgcn_s_barrier();

#pragma unroll
    for (int at = 0; at < 4; ++at) {
#pragma unroll
      for (int rg = 0; rg < 4; ++rg) {
        int rloc = wr * 64 + at * 16 + lq * 4 + rg;
        int rglob = row0 + rloc;
        float v[4];
#pragma unroll
        for (int ct = 0; ct < 4; ++ct) {
          int cg = col0 + wc * 64 + ct * 16 + lr;
          v[ct] = (cg < N && cg != rglob) ? acc[at][ct][rg] : NEGINF;
        }
        float m = fmaxf(fmaxf(v[0], v[1]), fmaxf(v[2], v[3]));
#pragma unroll
        for (int o = 1; o < 16; o <<= 1) m = fmaxf(m, __shfl_xor(m, o));
        float sv = __expf(v[0] - m) + __expf(v[1] - m) +
                   __expf(v[2] - m) + __expf(v[3] - m);
#pragma unroll
        for (int o = 1; o < 16; o <<= 1) sv += __shfl_xor(sv, o);
        if (lr == 0) { mS[wc][rloc] = m; sS[wc][rloc] = sv; }
      }
    }
    if (rb != sg) {
#pragma unroll
      for (int ct = 0; ct < 4; ++ct) {
        float m = NEGINF;
#pragma unroll
        for (int at = 0; at < 4; ++at)
#pragma unroll
          for (int rg = 0; rg < 4; ++rg) m = fmaxf(m, acc[at][ct][rg]);
        m = fmaxf(m, __shfl_xor(m, 16));
        m = fmaxf(m, __shfl_xor(m, 32));
        float s = 0.f;
#pragma unroll
        for (int at = 0; at < 4; ++at)
#pragma unroll
          for (int rg = 0; rg < 4; ++rg) s += __expf(acc[at][ct][rg] - m);
        s += __shfl_xor(s, 16);
        s += __shfl_xor(s, 32);
        if (lq == 0) {
          mC[wr][wc * 64 + ct * 16 + lr] = m;
          sC[wr][wc * 64 + ct * 16 + lr] = s;
        }
      }
    }
    __syncthreads();

    if (tid < 128) {
      int rglob = row0 + tid;
      if (rglob < N) {
        float m0 = mS[0][tid], m1 = mS[1][tid];
        float m = fmaxf(m0, m1);
        float sv = sS[0][tid] * __expf(m0 - m) + sS[1][tid] * __expf(m1 - m);
        int idx = (b * S + sg) * N + rglob;
        wm[idx] = m;
        wv[idx] = sv;
      }
      if (rb != sg) {
        float m0 = mC[0][tid], m1 = mC[1][tid];
        float m = fmaxf(m0, m1);
        float sv = sC[0][tid] * __expf(m0 - m) + sC[1][tid] * __expf(m1 - m);
        int idx = (b * S + rb) * N + col0 + tid;
        wm[idx] = m;
        wv[idx] = sv;
      }
    }
  } else {
    // instance levels 1..10: one wave per t
    int iw = 1024 + (bx - nTiles) * 4 + (tid >> 6);
    if (iw < tab.totInst) {
      int l = 1;
      while (iw >= tab.instStart[l + 1]) ++l;
      int t = iw - tab.instStart[l];
      int T = tab.T[l];
      const unsigned short* zz1 = z1 + tab.zoff[l];
      const unsigned short* zz2 = z2 + tab.zoff[l];
      int lane = tid & 63, lq = lane >> 4, lr = lane & 15;
      const unsigned short* zr = (lr < 8)
          ? zz1 + ((size_t)lr * T + t) * D_DIM
          : zz2 + ((size_t)(lr - 8) * T + t) * D_DIM;
      zr += lq * 8;
      f32x4_t c = (f32x4_t)(0.f);
#pragma unroll
      for (int k = 0; k < 10; ++k) {
        bf16x8_t a = *(const bf16x8_t*)(zr + k * 32);
        c = __builtin_amdgcn_mfma_f32_16x16x32_bf16(a, a, c, 0, 0, 0);
      }
      float lsum = 0.f;
#pragma unroll
      for (int rg = 0; rg < 4; ++rg) {
        int rrow = lq * 4 + rg;
        float v = c[rg];
        float x = (lr != rrow) ? v : NEGINF;
        float m = x;
#pragma unroll
        for (int o = 1; o < 16; o <<= 1) m = fmaxf(m, __shfl_xor(m, o));
        float s = __expf(x - m);
#pragma unroll
        for (int o = 1; o < 16; o <<= 1) s += __shfl_xor(s, o);
        int pos = (rrow < 8) ? rrow + 8 : rrow - 8;
        if (lr == pos) lsum += m + __logf(s) - v;
      }
#pragma unroll
      for (int o = 1; o < 64; o <<= 1) lsum += __shfl_xor(lsum, o);
      if (lane == 0) wsInst[iw] = lsum * tab.scale[l];
    }
  }
}

// ---------------- combine: temporal rows + instance partials -> out ----------
__global__ __launch_bounds__(256) void combine_kernel(
    const unsigned short* __restrict__ z1, const unsigned short* __restrict__ z2,
    const float* __restrict__ wsm, const float* __restrict__ wss,
    const float* __restrict__ wsInst, float* __restrict__ out, Tab tab) {
  int g = blockIdx.x * 256 + threadIdx.x;
  float loss = 0.f;
  if (g < tab.totr) {
    int l = 0;
    while (g >= tab.rstart[l + 1]) ++l;
    int row = g - tab.rstart[l];
    int T = tab.T[l], N = 2 * T, S = tab.S[l];
    int b = row / N, r = row % N;
    const float* wm = wsm + tab.wsoff[l];
    const float* wv = wss + tab.wsoff[l];
    float m = NEGINF;
    for (int s = 0; s < S; ++s) m = fmaxf(m, wm[(b * S + s) * N + r]);
    float sv = 0.f;
    for (int s = 0; s < S; ++s) {
      int idx = (b * S + s) * N + r;
      sv += wv[idx] * __expf(wm[idx] - m);
    }
    const unsigned short* zz1 = z1 + tab.zoff[l];
    const unsigned short* zz2 = z2 + tab.zoff[l];
    int pos = (r < T) ? r + T : r - T;
    const bf16x8_t* za = (const bf16x8_t*)zrowb(zz1, zz2, b, T, r);
    const bf16x8_t* zp = (const bf16x8_t*)zrowb(zz1, zz2, b, T, pos);
    float dot = 0.f;
    for (int k = 0; k < D_DIM / 8; ++k) {
      bf16x8_t a = za[k], p = zp[k];
#pragma unroll
      for (int e = 0; e < 8; ++e)
        dot += bf2f((unsigned short)a[e]) * bf2f((unsigned short)p[e]);
    }
    loss = (m + logf(sv) - dot) * tab.scale[l];
  } else if (g < tab.totr + tab.totInst) {
    loss = wsInst[g - tab.totr];
  }
  float v = loss;
#pragma unroll
  for (int o = 1; o < 64; o <<= 1) v += __shfl_xor(v, o);
  __shared__ float part[4];
  int w = threadIdx.x >> 6;
  if ((threadIdx.x & 63) == 0) part[w] = v;
  __syncthreads();
  if (threadIdx.x == 0)
    atomicAdd(out, part[0] + part[1] + part[2] + part[3]);
}

extern "C" void kernel_launch(void* const* d_in, const int* in_sizes, int n_in,
                              void* d_out, int out_size, void* d_ws, size_t ws_size,
                              hipStream_t stream) {
  const float* z1_in = (const float*)d_in[0];
  const float* z2_in = (const float*)d_in[1];
  const int* time_in = (const int*)d_in[2];
  float* out = (float*)d_out;

  // ---- level tables (triangular tile counts) ----
  Tab tab;
  int zo = 0, wso = 0, ts = 0, is = 0, rs = 0;
  for (int l = 0; l < 11; ++l) {
    int T = 1024 >> l, N = 2 * T;
    int S = (N >= 128) ? N / 128 : 1;
    tab.T[l] = T;
    tab.S[l] = S;
    tab.zoff[l] = zo;
    tab.scale[l] = 1.0f / (352.0f * (float)T);  // 0.5/(2*B*T)/11
    tab.tileStart[l] = ts;
    tab.instStart[l] = is;
    tab.wsoff[l] = (T > 1) ? wso : 0;
    if (l < 10) tab.rstart[l] = rs;
    if (T > 1) {
      ts += 8 * ((S * (S + 1)) >> 1);
      wso += 8 * S * N;
      rs += 8 * N;
    }
    is += T;
    zo += 8 * T * D_DIM;
  }
  tab.tileStart[11] = ts;
  tab.instStart[11] = is;
  tab.rstart[10] = rs;
  tab.totTemp = ts;
  tab.totInst = is;
  tab.totr = rs;

  // ---- workspace carve ----
  char* w = (char*)d_ws;
  unsigned short* z1s = (unsigned short*)w; w += (size_t)zo * 2;
  unsigned short* z2s = (unsigned short*)w; w += (size_t)zo * 2;
  int* sel_all = (int*)w; w += 8192 * sizeof(int);
  float* wsm = (float*)w; w += (size_t)wso * sizeof(float);
  float* wss = (float*)w; w += (size_t)wso * sizeof(float);
  float* wsInst = (float*)w; w += (size_t)is * sizeof(float);

  int n0 = 8 * 1024 * D_DIM;
  int nconv = 504;
  prep_kernel<<<8 + nconv, 1024, 0, stream>>>(time_in, sel_all, z1_in, z2_in,
                                              z1s, z2s, n0 / 4, out, out_size,
                                              nconv);
  l0_kernel<<<1984, 256, 0, stream>>>(sel_all, z1s, z2s, wsm, wss, wsInst);
  int nInstB = (tab.totInst - 1024 + 3) / 4;
  rest_kernel<<<(tab.totTemp - tab.tileStart[1]) + nInstB, 256, 0, stream>>>(
      z1s, z2s, wsm, wss, wsInst, tab);
  combine_kernel<<<(tab.totr + tab.totInst + 255) / 256, 256, 0, stream>>>(
      z1s, z2s, wsm, wss, wsInst, out, tab);
}